// Round 3
// baseline (452.406 us; speedup 1.0000x reference)
//
#include <hip/hip_runtime.h>
#include <hip/hip_bf16.h>
#include <stdint.h>

#define DIMSZ 1024
#define BN_TOT 8192   // B*N
#define NSEQ 2048
#define NHEADS 16
#define DHEAD 64

typedef __attribute__((ext_vector_type(8))) __bf16 bf16x8;
typedef __attribute__((ext_vector_type(4))) float f32x4;

__device__ __forceinline__ float bf2f(ushort u) {
  return __uint_as_float(((uint32_t)u) << 16);
}
__device__ __forceinline__ ushort f2bf(float f) {
  uint32_t u = __float_as_uint(f);
  u += 0x7FFFu + ((u >> 16) & 1u);   // round-to-nearest-even
  return (ushort)(u >> 16);
}
// pack two f32 -> two bf16 in one u32 (RNE), lo = first operand
__device__ __forceinline__ uint32_t cvt_pk_bf16(float lo, float hi) {
  uint32_t r;
  asm("v_cvt_pk_bf16_f32 %0, %1, %2" : "=v"(r) : "v"(lo), "v"(hi));
  return r;
}
// async global -> LDS, 16B per lane. LDS dest must be wave-uniform base.
__device__ __forceinline__ void gl_lds16(const ushort* g, ushort* l) {
  __builtin_amdgcn_global_load_lds(
      (const __attribute__((address_space(1))) void*)g,
      (__attribute__((address_space(3))) void*)l, 16, 0, 0);
}

// ---------------- LayerNorm: x[8192][1024] f32 -> xn bf16 ----------------
__global__ __launch_bounds__(256) void layernorm_k(
    const float* __restrict__ x, const float* __restrict__ gamma,
    const float* __restrict__ beta, ushort* __restrict__ xn) {
  const int row = blockIdx.x;
  const int tid = threadIdx.x;
  const float* xr = x + (size_t)row * DIMSZ;
  float4 v = *(const float4*)(xr + tid * 4);
  float s = v.x + v.y + v.z + v.w;
  float ss = v.x * v.x + v.y * v.y + v.z * v.z + v.w * v.w;
#pragma unroll
  for (int o = 1; o < 64; o <<= 1) { s += __shfl_xor(s, o); ss += __shfl_xor(ss, o); }
  __shared__ float red[2][4];
  const int wid = tid >> 6;
  if ((tid & 63) == 0) { red[0][wid] = s; red[1][wid] = ss; }
  __syncthreads();
  s = red[0][0] + red[0][1] + red[0][2] + red[0][3];
  ss = red[1][0] + red[1][1] + red[1][2] + red[1][3];
  const float mu = s * (1.0f / DIMSZ);
  const float var = ss * (1.0f / DIMSZ) - mu * mu;
  const float rstd = rsqrtf(var + 1e-5f);
  float4 g = *(const float4*)(gamma + tid * 4);
  float4 bb = *(const float4*)(beta + tid * 4);
  ushort4 o4;
  o4.x = f2bf((v.x - mu) * rstd * g.x + bb.x);
  o4.y = f2bf((v.y - mu) * rstd * g.y + bb.y);
  o4.z = f2bf((v.z - mu) * rstd * g.z + bb.z);
  o4.w = f2bf((v.w - mu) * rstd * g.w + bb.w);
  *(ushort4*)(xn + (size_t)row * DIMSZ + tid * 4) = o4;
}

// ------------- row L2-normalize + exact GELU: sim f32 -> bf16 -------------
__global__ __launch_bounds__(256) void normgelu_k(
    const float* __restrict__ sim, ushort* __restrict__ out) {
  const int row = blockIdx.x;
  const int tid = threadIdx.x;
  const float* sr = sim + (size_t)row * DIMSZ;
  float4 v = *(const float4*)(sr + tid * 4);
  float ss = v.x * v.x + v.y * v.y + v.z * v.z + v.w * v.w;
#pragma unroll
  for (int o = 1; o < 64; o <<= 1) ss += __shfl_xor(ss, o);
  __shared__ float red[4];
  if ((tid & 63) == 0) red[tid >> 6] = ss;
  __syncthreads();
  ss = red[0] + red[1] + red[2] + red[3];
  const float inv = 1.0f / fmaxf(sqrtf(ss), 1e-12f);
  ushort4 o4;
  float x0;
  x0 = v.x * inv; o4.x = f2bf(0.5f * x0 * (1.0f + erff(x0 * 0.70710678118654752f)));
  x0 = v.y * inv; o4.y = f2bf(0.5f * x0 * (1.0f + erff(x0 * 0.70710678118654752f)));
  x0 = v.z * inv; o4.z = f2bf(0.5f * x0 * (1.0f + erff(x0 * 0.70710678118654752f)));
  x0 = v.w * inv; o4.w = f2bf(0.5f * x0 * (1.0f + erff(x0 * 0.70710678118654752f)));
  *(ushort4*)(out + (size_t)row * DIMSZ + tid * 4) = o4;
}

// --------------------- f32 -> bf16 copy (weights) ---------------------
__global__ void cvt_k(const float* __restrict__ in, ushort* __restrict__ out, int n) {
  int i = (blockIdx.x * 256 + threadIdx.x) * 4;
  if (i < n) {
    float4 v = *(const float4*)(in + i);
    ushort4 o;
    o.x = f2bf(v.x); o.y = f2bf(v.y); o.z = f2bf(v.z); o.w = f2bf(v.w);
    *(ushort4*)(out + i) = o;
  }
}

// ---------- transpose + convert: val [P][E] f32 -> valT [E][P] bf16 ----------
__global__ __launch_bounds__(256) void transpose_cvt_k(
    const float* __restrict__ in, ushort* __restrict__ out) {
  __shared__ float t[32][33];
  const int tx = threadIdx.x & 31;
  const int ty = threadIdx.x >> 5;  // 0..7
  const int bx = blockIdx.x * 32;   // col block of in (E)
  const int by = blockIdx.y * 32;   // row block of in (P)
#pragma unroll
  for (int i = 0; i < 32; i += 8)
    t[ty + i][tx] = in[(size_t)(by + ty + i) * DIMSZ + bx + tx];
  __syncthreads();
#pragma unroll
  for (int i = 0; i < 32; i += 8)
    out[(size_t)(bx + ty + i) * DIMSZ + by + tx] = f2bf(t[tx][ty + i]);
}

// ---- V transpose (bf16): vb[8192][1024] -> vt[64 bh][64 d][2048 n] ----
__global__ __launch_bounds__(256) void transpose_v_k(
    const ushort* __restrict__ vb, ushort* __restrict__ vt) {
  __shared__ ushort t[32][33];
  const int bh = blockIdx.x;        // 0..63
  const int nt = blockIdx.y;        // 0..63 (n tile)
  const int dt = blockIdx.z;        // 0..1  (d tile)
  const int b = bh >> 4, h = bh & 15;
  const int tx = threadIdx.x & 31;
  const int ty = threadIdx.x >> 5;  // 0..7
  const size_t inbase = ((size_t)b * NSEQ + nt * 32) * DIMSZ + h * DHEAD + dt * 32;
#pragma unroll
  for (int i = 0; i < 32; i += 8)
    t[ty + i][tx] = vb[inbase + (size_t)(ty + i) * DIMSZ + tx];   // t[n][d]
  __syncthreads();
  const size_t outbase = ((size_t)bh * DHEAD + dt * 32) * NSEQ + nt * 32;
#pragma unroll
  for (int i = 0; i < 32; i += 8)
    vt[outbase + (size_t)(ty + i) * NSEQ + tx] = t[tx][ty + i];   // out[d][n]
}

// ---------------- bf16 MFMA NT-GEMM: C[M,N] = A[M,K] * B[N,K]^T ----------------
// m97 structure: 128x128 tile, BK=32, 4 waves (2x2), global_load_lds width-16
// direct staging into linear LDS [128][32] (no pad: gload_lds needs contiguous
// lane-order destination). 2-barrier loop; compiler drains vmcnt at barrier.
template <int OUT_BF16>
__global__ __launch_bounds__(256) void gemm_nt_k(
    const ushort* __restrict__ A, const ushort* __restrict__ B,
    void* __restrict__ Cout, int M, int N, int K) {
  __shared__ ushort As[128 * 32];
  __shared__ ushort Bs[128 * 32];
  const int tid = threadIdx.x;
  const int lane = tid & 63;
  const int wid = tid >> 6;
  const int i0 = blockIdx.x * 128;
  const int n0 = blockIdx.y * 128;
  const int wr = (wid >> 1) * 64;
  const int wc = (wid & 1) * 64;
  f32x4 acc[4][4];
#pragma unroll
  for (int m = 0; m < 4; ++m)
#pragma unroll
    for (int n = 0; n < 4; ++n) acc[m][n] = (f32x4){0.f, 0.f, 0.f, 0.f};
  const int fr = lane & 15;
  const int kg = (lane >> 4) * 8;
  // staging: wave w covers rows w*32..w*32+31 of each tile (2 instrs of 16 rows)
  const int srow = wid * 32 + (lane >> 2);
  const int skc = (lane & 3) * 8;
  const ushort* Ag = A + (size_t)(i0 + srow) * K + skc;
  const ushort* Bg = B + (size_t)(n0 + srow) * K + skc;
  ushort* AsW = As + wid * 1024;   // wave-uniform LDS base (shorts)
  ushort* BsW = Bs + wid * 1024;
  for (int k0 = 0; k0 < K; k0 += 32) {
    __syncthreads();                       // prev frag reads done
    gl_lds16(Ag + k0, AsW);                // rows w*32 + 0..15
    gl_lds16(Ag + (size_t)16 * K + k0, AsW + 512);  // rows w*32 + 16..31
    gl_lds16(Bg + k0, BsW);
    gl_lds16(Bg + (size_t)16 * K + k0, BsW + 512);
    __syncthreads();                       // vmcnt drained -> tile in LDS
    bf16x8 af[4], bfr[4];
#pragma unroll
    for (int m = 0; m < 4; ++m)
      af[m] = *(const bf16x8*)&As[(wr + m * 16 + fr) * 32 + kg];
#pragma unroll
    for (int n = 0; n < 4; ++n)
      bfr[n] = *(const bf16x8*)&Bs[(wc + n * 16 + fr) * 32 + kg];
#pragma unroll
    for (int m = 0; m < 4; ++m)
#pragma unroll
      for (int n = 0; n < 4; ++n)
        acc[m][n] = __builtin_amdgcn_mfma_f32_16x16x32_bf16(af[m], bfr[n], acc[m][n], 0, 0, 0);
  }
  const int rq = lane >> 4;
#pragma unroll
  for (int m = 0; m < 4; ++m) {
#pragma unroll
    for (int n = 0; n < 4; ++n) {
#pragma unroll
      for (int rr = 0; rr < 4; ++rr) {
        const int row = i0 + wr + m * 16 + rq * 4 + rr;
        const int col = n0 + wc + n * 16 + fr;
        if (OUT_BF16)
          ((ushort*)Cout)[(size_t)row * N + col] = f2bf(acc[m][n][rr]);
        else
          ((float*)Cout)[(size_t)row * N + col] = acc[m][n][rr];
      }
    }
  }
}

// ---------------- MFMA bf16 flash attention (swapped-operand) ----------------
// Block = 256 threads (4 waves) = one (b,h) x 128 q-rows; wave owns 32 q-rows.
// KV tiles of 64. K staged [kv][d], V staged pre-transposed [d][kv].
// S^T = mfma(K, Q): q = lane-local column -> in-lane softmax reduce.
// Defer-max (THR=8, log2 domain): skip alpha-rescale unless max grows.
// P packed bf16 via cvt_pk -> per-wave LDS slab -> O^T = mfma(V^T, P).
__global__ __launch_bounds__(256, 4) void flash_mfma_k(
    const ushort* __restrict__ Qm, const ushort* __restrict__ Km,
    const ushort* __restrict__ Vt, ushort* __restrict__ Om) {
  __shared__ ushort Ks[64 * 72];
  __shared__ ushort Vs[64 * 72];      // V^T tile: [d][kv]
  __shared__ ushort Ps[4][32 * 72];   // per-wave P tile [q][kv]
  const int tid = threadIdx.x;
  const int lane = tid & 63;
  const int wid = tid >> 6;
  const int bh = blockIdx.x;          // 0..63
  const int qb = blockIdx.y;          // 0..15
  const int bidx = bh >> 4;
  const int h = bh & 15;
  const size_t rowbase = (size_t)bidx * NSEQ;
  const int colbase = h * DHEAD;
  const int fr = lane & 15;           // A-row / B-col select; q = m*16+fr
  const int g = lane >> 4;
  const int kg = g * 8;
  const int q0 = qb * 128 + wid * 32;

  // Q fragments in registers (used as B operand), reused across all KV tiles
  bf16x8 qf[2][2];
#pragma unroll
  for (int m = 0; m < 2; ++m)
#pragma unroll
    for (int ks = 0; ks < 2; ++ks)
      qf[m][ks] = *(const bf16x8*)(Qm + (rowbase + q0 + m * 16 + fr) * (size_t)DIMSZ +
                                   colbase + ks * 32 + kg);

  // O^T accumulator: col = q = m*16+fr, row = d = nd*16 + g*4 + rr
  f32x4 oaccT[2][4];
#pragma unroll
  for (int m = 0; m < 2; ++m)
#pragma unroll
    for (int n = 0; n < 4; ++n) oaccT[m][n] = (f32x4){0.f, 0.f, 0.f, 0.f};
  float m2[2] = {-1e30f, -1e30f};     // running max, log2-scaled domain
  float l_run[2] = {0.f, 0.f};
  const float c1 = 0.125f * 1.44269504088896340736f;  // scale * log2(e)

  const ushort* Kg = Km + rowbase * DIMSZ + colbase;
  const ushort* Vg = Vt + (size_t)bh * DHEAD * NSEQ;
  const int sr = tid >> 3;            // 0..31 staging row
  const int c8 = (tid & 7) * 8;

  // prologue: load tile 0
  uint4 k0 = *(const uint4*)(Kg + (size_t)sr * DIMSZ + c8);
  uint4 k1 = *(const uint4*)(Kg + (size_t)(sr + 32) * DIMSZ + c8);
  uint4 v0 = *(const uint4*)(Vg + (size_t)sr * NSEQ + c8);
  uint4 v1 = *(const uint4*)(Vg + (size_t)(sr + 32) * NSEQ + c8);

  for (int kt = 0; kt < NSEQ / 64; ++kt) {
    __syncthreads();                  // prev tile's LDS reads done
    *(uint4*)&Ks[sr * 72 + c8] = k0;
    *(uint4*)&Ks[(sr + 32) * 72 + c8] = k1;
    *(uint4*)&Vs[sr * 72 + c8] = v0;
    *(uint4*)&Vs[(sr + 32) * 72 + c8] = v1;
    __syncthreads();
    if (kt + 1 < NSEQ / 64) {         // prefetch next tile under compute
      k0 = *(const uint4*)(Kg + (size_t)((kt + 1) * 64 + sr) * DIMSZ + c8);
      k1 = *(const uint4*)(Kg + (size_t)((kt + 1) * 64 + sr + 32) * DIMSZ + c8);
      v0 = *(const uint4*)(Vg + (size_t)sr * NSEQ + (kt + 1) * 64 + c8);
      v1 = *(const uint4*)(Vg + (size_t)(sr + 32) * NSEQ + (kt + 1) * 64 + c8);
    }

    // ---- S^T = K Q^T : s[m][n][rr] = S[q=m*16+fr][kv=n*16+g*4+rr] ----
    f32x4 s[2][4];
#pragma unroll
    for (int m = 0; m < 2; ++m)
#pragma unroll
      for (int n = 0; n < 4; ++n) s[m][n] = (f32x4){0.f, 0.f, 0.f, 0.f};
    __builtin_amdgcn_s_setprio(1);
#pragma unroll
    for (int ks = 0; ks < 2; ++ks) {
      bf16x8 ak[4];
#pragma unroll
      for (int n = 0; n < 4; ++n)
        ak[n] = *(const bf16x8*)&Ks[(n * 16 + fr) * 72 + ks * 32 + kg];
#pragma unroll
      for (int m = 0; m < 2; ++m)
#pragma unroll
        for (int n = 0; n < 4; ++n)
          s[m][n] = __builtin_amdgcn_mfma_f32_16x16x32_bf16(ak[n], qf[m][ks], s[m][n], 0, 0, 0);
    }
    __builtin_amdgcn_s_setprio(0);

    // ---- online softmax, kv lane-local; defer-max (THR=8 in log2 domain) ----
#pragma unroll
    for (int m = 0; m < 2; ++m) {
      float tm = fmaxf(fmaxf(fmaxf(s[m][0][0], s[m][0][1]), fmaxf(s[m][0][2], s[m][0][3])),
                       fmaxf(fmaxf(s[m][1][0], s[m][1][1]), fmaxf(s[m][1][2], s[m][1][3])));
      tm = fmaxf(tm,
                 fmaxf(fmaxf(fmaxf(s[m][2][0], s[m][2][1]), fmaxf(s[m][2][2], s[m][2][3])),
                       fmaxf(fmaxf(s[m][3][0], s[m][3][1]), fmaxf(s[m][3][2], s[m][3][3]))));
      tm = fmaxf(tm, __shfl_xor(tm, 16));
      tm = fmaxf(tm, __shfl_xor(tm, 32));
      const float tm2 = tm * c1;
      if (!__all(tm2 <= m2[m] + 8.0f)) {  // wave-uniform: rescale only on growth
        const float mn2 = fmaxf(m2[m], tm2);
        const float al = exp2f(m2[m] - mn2);
        l_run[m] *= al;
        m2[m] = mn2;
#pragma unroll
        for (int n = 0; n < 4; ++n) oaccT[m][n] *= al;
      }
      const float mref = m2[m];
      float p[4][4];
#pragma unroll
      for (int n = 0; n < 4; ++n)
#pragma unroll
        for (int rr = 0; rr < 4; ++rr) {
          p[n][rr] = exp2f(fmaf(s[m][n][rr], c1, -mref));
          s[m][n][rr] = p[n][rr];
        }
      // tree-shaped sum (short dependency chain)
      const float t0 = (p[0][0] + p[0][1]) + (p[0][2] + p[0][3]);
      const float t1 = (p[1][0] + p[1][1]) + (p[1][2] + p[1][3]);
      const float t2 = (p[2][0] + p[2][1]) + (p[2][2] + p[2][3]);
      const float t3 = (p[3][0] + p[3][1]) + (p[3][2] + p[3][3]);
      float ps = (t0 + t1) + (t2 + t3);
      ps += __shfl_xor(ps, 16);
      ps += __shfl_xor(ps, 32);
      l_run[m] += ps;
    }

    // ---- P^T -> Ps[wid] as [q][kv], packed b64 writes ----
    ushort* pw = &Ps[wid][0];
#pragma unroll
    for (int m = 0; m < 2; ++m)
#pragma unroll
      for (int n = 0; n < 4; ++n) {
        uint2 w;
        w.x = cvt_pk_bf16(s[m][n][0], s[m][n][1]);
        w.y = cvt_pk_bf16(s[m][n][2], s[m][n][3]);
        *(uint2*)&pw[(m * 16 + fr) * 72 + n * 16 + g * 4] = w;
      }

    // ---- O^T += V^T P : oaccT[m][nd], col=q=m*16+fr, row=d=nd*16+g*4+rr ----
    __builtin_amdgcn_s_setprio(1);
#pragma unroll
    for (int ks = 0; ks < 2; ++ks) {
      bf16x8 av[4], pb[2];
#pragma unroll
      for (int nd = 0; nd < 4; ++nd)
        av[nd] = *(const bf16x8*)&Vs[(nd * 16 + fr) * 72 + ks * 32 + kg];
#pragma unroll
      for (int m = 0; m < 2; ++m)
        pb[m] = *(const bf16x8*)&Ps[wid][(m * 16 + fr) * 72 + ks * 32 + kg];
#pragma unroll
      for (int m = 0; m < 2; ++m)
#pragma unroll
        for (int nd = 0; nd < 4; ++nd)
          oaccT[m][nd] = __builtin_amdgcn_mfma_f32_16x16x32_bf16(av[nd], pb[m], oaccT[m][nd], 0, 0, 0);
    }
    __builtin_amdgcn_s_setprio(0);
  }

  // ---- epilogue: O / l, packed b64 global writes ----
#pragma unroll
  for (int m = 0; m < 2; ++m) {
    const float invl = 1.0f / l_run[m];
    const size_t row = rowbase + q0 + m * 16 + fr;
#pragma unroll
    for (int nd = 0; nd < 4; ++nd) {
      uint2 w;
      w.x = cvt_pk_bf16(oaccT[m][nd][0] * invl, oaccT[m][nd][1] * invl);
      w.y = cvt_pk_bf16(oaccT[m][nd][2] * invl, oaccT[m][nd][3] * invl);
      *(uint2*)(Om + row * DIMSZ + colbase + nd * 16 + g * 4) = w;
    }
  }
}

extern "C" void kernel_launch(void* const* d_in, const int* in_sizes, int n_in,
                              void* d_out, int out_size, void* d_ws, size_t ws_size,
                              hipStream_t stream) {
  (void)in_sizes; (void)n_in; (void)out_size; (void)ws_size;
  const float* x     = (const float*)d_in[0];
  const float* ln_g  = (const float*)d_in[1];
  const float* ln_b  = (const float*)d_in[2];
  const float* q_key = (const float*)d_in[3];
  const float* q_val = (const float*)d_in[4];
  const float* k_key = (const float*)d_in[5];
  const float* k_val = (const float*)d_in[6];
  const float* v_key = (const float*)d_in[7];
  const float* v_val = (const float*)d_in[8];
  const float* o_key = (const float*)d_in[9];
  const float* o_val = (const float*)d_in[10];
  float* out = (float*)d_out;

  char* ws = (char*)d_ws;
  const size_t MB = 1024 * 1024;
  ushort* xn    = (ushort*)(ws + 0 * MB);    // 16MB: x_norm bf16 [8192][1024]
  ushort* wkey  = (ushort*)(ws + 16 * MB);   // 8MB: 4x key bf16 [1024][1024]
  ushort* wvalT = (ushort*)(ws + 24 * MB);   // 8MB: 4x val^T bf16 [1024][1024]
  ushort* gelu  = (ushort*)(ws + 32 * MB);   // 16MB: gelu(sim/nrm) bf16
  ushort* qb    = (ushort*)(ws + 48 * MB);   // 16MB
  ushort* kb    = (ushort*)(ws + 64 * MB);   // 16MB
  ushort* vb    = (ushort*)(ws + 80 * MB);   // 16MB
  ushort* aout  = (ushort*)(ws + 96 * MB);   // 16MB: attention output bf16
  // vt aliases gelu: gelu contents are dead between the last pre-attn gemm
  // and the post-attn normgelu, which is exactly vt's live range.
  ushort* vt    = gelu;                      // 16MB: V^T bf16 [64 bh][64 d][2048 n]
  float* sim = (float*)d_out;                // reuse d_out (32MB f32) as sim scratch

  const int NW = DIMSZ * DIMSZ;

  layernorm_k<<<BN_TOT, 256, 0, stream>>>(x, ln_g, ln_b, xn);
  cvt_k<<<1024, 256, 0, stream>>>(q_key, wkey + 0 * (size_t)NW, NW);
  cvt_k<<<1024, 256, 0, stream>>>(k_key, wkey + 1 * (size_t)NW, NW);
  cvt_k<<<1024, 256, 0, stream>>>(v_key, wkey + 2 * (size_t)NW, NW);
  cvt_k<<<1024, 256, 0, stream>>>(o_key, wkey + 3 * (size_t)NW, NW);
  dim3 tg(32, 32);
  transpose_cvt_k<<<tg, 256, 0, stream>>>(q_val, wvalT + 0 * (size_t)NW);
  transpose_cvt_k<<<tg, 256, 0, stream>>>(k_val, wvalT + 1 * (size_t)NW);
  transpose_cvt_k<<<tg, 256, 0, stream>>>(v_val, wvalT + 2 * (size_t)NW);
  transpose_cvt_k<<<tg, 256, 0, stream>>>(o_val, wvalT + 3 * (size_t)NW);

  dim3 gg(BN_TOT / 128, DIMSZ / 128);
  ushort* outs[3] = {qb, kb, vb};
  for (int t = 0; t < 3; ++t) {
    gemm_nt_k<0><<<gg, 256, 0, stream>>>(xn, wkey + t * (size_t)NW, sim, BN_TOT, DIMSZ, DIMSZ);
    normgelu_k<<<BN_TOT, 256, 0, stream>>>(sim, gelu);
    gemm_nt_k<1><<<gg, 256, 0, stream>>>(gelu, wvalT + t * (size_t)NW, outs[t], BN_TOT, DIMSZ, DIMSZ);
  }
  transpose_v_k<<<dim3(64, 64, 2), 256, 0, stream>>>(vb, vt);
  flash_mfma_k<<<dim3(64, 16), 256, 0, stream>>>(qb, kb, vt, aout);
  gemm_nt_k<0><<<gg, 256, 0, stream>>>(aout, wkey + 3 * (size_t)NW, sim, BN_TOT, DIMSZ, DIMSZ);
  normgelu_k<<<BN_TOT, 256, 0, stream>>>(sim, gelu);
  gemm_nt_k<0><<<gg, 256, 0, stream>>>(gelu, wvalT + 3 * (size_t)NW, (void*)out, BN_TOT, DIMSZ, DIMSZ);
}

// Round 4
// 431.953 us; speedup vs baseline: 1.0473x; 1.0473x over previous
//
#include <hip/hip_runtime.h>
#include <hip/hip_bf16.h>
#include <stdint.h>

#define DIMSZ 1024
#define BN_TOT 8192   // B*N
#define NSEQ 2048
#define NHEADS 16
#define DHEAD 64

typedef __attribute__((ext_vector_type(8))) __bf16 bf16x8;
typedef __attribute__((ext_vector_type(4))) float f32x4;

__device__ __forceinline__ float bf2f(ushort u) {
  return __uint_as_float(((uint32_t)u) << 16);
}
__device__ __forceinline__ ushort f2bf(float f) {
  uint32_t u = __float_as_uint(f);
  u += 0x7FFFu + ((u >> 16) & 1u);   // round-to-nearest-even
  return (ushort)(u >> 16);
}
// pack two f32 -> two bf16 in one u32 (RNE), lo = first operand
__device__ __forceinline__ uint32_t cvt_pk_bf16(float lo, float hi) {
  uint32_t r;
  asm("v_cvt_pk_bf16_f32 %0, %1, %2" : "=v"(r) : "v"(lo), "v"(hi));
  return r;
}
// async global -> LDS, 16B per lane. LDS dest must be wave-uniform base.
__device__ __forceinline__ void gl_lds16(const ushort* g, ushort* l) {
  __builtin_amdgcn_global_load_lds(
      (const __attribute__((address_space(1))) void*)g,
      (__attribute__((address_space(3))) void*)l, 16, 0, 0);
}

// ---------------- LayerNorm: x[8192][1024] f32 -> xn bf16 ----------------
__global__ __launch_bounds__(256) void layernorm_k(
    const float* __restrict__ x, const float* __restrict__ gamma,
    const float* __restrict__ beta, ushort* __restrict__ xn) {
  const int row = blockIdx.x;
  const int tid = threadIdx.x;
  const float* xr = x + (size_t)row * DIMSZ;
  float4 v = *(const float4*)(xr + tid * 4);
  float s = v.x + v.y + v.z + v.w;
  float ss = v.x * v.x + v.y * v.y + v.z * v.z + v.w * v.w;
#pragma unroll
  for (int o = 1; o < 64; o <<= 1) { s += __shfl_xor(s, o); ss += __shfl_xor(ss, o); }
  __shared__ float red[2][4];
  const int wid = tid >> 6;
  if ((tid & 63) == 0) { red[0][wid] = s; red[1][wid] = ss; }
  __syncthreads();
  s = red[0][0] + red[0][1] + red[0][2] + red[0][3];
  ss = red[1][0] + red[1][1] + red[1][2] + red[1][3];
  const float mu = s * (1.0f / DIMSZ);
  const float var = ss * (1.0f / DIMSZ) - mu * mu;
  const float rstd = rsqrtf(var + 1e-5f);
  float4 g = *(const float4*)(gamma + tid * 4);
  float4 bb = *(const float4*)(beta + tid * 4);
  ushort4 o4;
  o4.x = f2bf((v.x - mu) * rstd * g.x + bb.x);
  o4.y = f2bf((v.y - mu) * rstd * g.y + bb.y);
  o4.z = f2bf((v.z - mu) * rstd * g.z + bb.z);
  o4.w = f2bf((v.w - mu) * rstd * g.w + bb.w);
  *(ushort4*)(xn + (size_t)row * DIMSZ + tid * 4) = o4;
}

// ------------- row L2-normalize + exact GELU: sim f32 -> bf16 -------------
__global__ __launch_bounds__(256) void normgelu_k(
    const float* __restrict__ sim, ushort* __restrict__ out) {
  const int row = blockIdx.x;
  const int tid = threadIdx.x;
  const float* sr = sim + (size_t)row * DIMSZ;
  float4 v = *(const float4*)(sr + tid * 4);
  float ss = v.x * v.x + v.y * v.y + v.z * v.z + v.w * v.w;
#pragma unroll
  for (int o = 1; o < 64; o <<= 1) ss += __shfl_xor(ss, o);
  __shared__ float red[4];
  if ((tid & 63) == 0) red[tid >> 6] = ss;
  __syncthreads();
  ss = red[0] + red[1] + red[2] + red[3];
  const float inv = 1.0f / fmaxf(sqrtf(ss), 1e-12f);
  ushort4 o4;
  float x0;
  x0 = v.x * inv; o4.x = f2bf(0.5f * x0 * (1.0f + erff(x0 * 0.70710678118654752f)));
  x0 = v.y * inv; o4.y = f2bf(0.5f * x0 * (1.0f + erff(x0 * 0.70710678118654752f)));
  x0 = v.z * inv; o4.z = f2bf(0.5f * x0 * (1.0f + erff(x0 * 0.70710678118654752f)));
  x0 = v.w * inv; o4.w = f2bf(0.5f * x0 * (1.0f + erff(x0 * 0.70710678118654752f)));
  *(ushort4*)(out + (size_t)row * DIMSZ + tid * 4) = o4;
}

// --------------------- f32 -> bf16 copy (weights) ---------------------
__global__ void cvt_k(const float* __restrict__ in, ushort* __restrict__ out, int n) {
  int i = (blockIdx.x * 256 + threadIdx.x) * 4;
  if (i < n) {
    float4 v = *(const float4*)(in + i);
    ushort4 o;
    o.x = f2bf(v.x); o.y = f2bf(v.y); o.z = f2bf(v.z); o.w = f2bf(v.w);
    *(ushort4*)(out + i) = o;
  }
}

// ---------- transpose + convert: val [P][E] f32 -> valT [E][P] bf16 ----------
__global__ __launch_bounds__(256) void transpose_cvt_k(
    const float* __restrict__ in, ushort* __restrict__ out) {
  __shared__ float t[32][33];
  const int tx = threadIdx.x & 31;
  const int ty = threadIdx.x >> 5;  // 0..7
  const int bx = blockIdx.x * 32;   // col block of in (E)
  const int by = blockIdx.y * 32;   // row block of in (P)
#pragma unroll
  for (int i = 0; i < 32; i += 8)
    t[ty + i][tx] = in[(size_t)(by + ty + i) * DIMSZ + bx + tx];
  __syncthreads();
#pragma unroll
  for (int i = 0; i < 32; i += 8)
    out[(size_t)(bx + ty + i) * DIMSZ + by + tx] = f2bf(t[tx][ty + i]);
}

// ---- V transpose (bf16): vb[8192][1024] -> vt[64 bh][64 d][2048 n] ----
__global__ __launch_bounds__(256) void transpose_v_k(
    const ushort* __restrict__ vb, ushort* __restrict__ vt) {
  __shared__ ushort t[32][33];
  const int bh = blockIdx.x;        // 0..63
  const int nt = blockIdx.y;        // 0..63 (n tile)
  const int dt = blockIdx.z;        // 0..1  (d tile)
  const int b = bh >> 4, h = bh & 15;
  const int tx = threadIdx.x & 31;
  const int ty = threadIdx.x >> 5;  // 0..7
  const size_t inbase = ((size_t)b * NSEQ + nt * 32) * DIMSZ + h * DHEAD + dt * 32;
#pragma unroll
  for (int i = 0; i < 32; i += 8)
    t[ty + i][tx] = vb[inbase + (size_t)(ty + i) * DIMSZ + tx];   // t[n][d]
  __syncthreads();
  const size_t outbase = ((size_t)bh * DHEAD + dt * 32) * NSEQ + nt * 32;
#pragma unroll
  for (int i = 0; i < 32; i += 8)
    vt[outbase + (size_t)(ty + i) * NSEQ + tx] = t[tx][ty + i];   // out[d][n]
}

// ---------------- bf16 MFMA NT-GEMM: C[M,N] = A[M,K] * B[N,K]^T ----------------
// 128x128 tile, BK=32, 4 waves (2x2). Double-buffered global_load_lds (T3
// minimum 2-phase): issue next tile's gl_lds into buf[cur^1] BEFORE computing
// buf[cur]; single barrier per iter drains vmcnt AFTER the MFMAs, so global
// latency hides under compute. Linear LDS [128][32] (gload_lds lane-order dest).
template <int OUT_BF16>
__global__ __launch_bounds__(256) void gemm_nt_k(
    const ushort* __restrict__ A, const ushort* __restrict__ B,
    void* __restrict__ Cout, int M, int N, int K) {
  __shared__ ushort As[2][128 * 32];
  __shared__ ushort Bs[2][128 * 32];
  const int tid = threadIdx.x;
  const int lane = tid & 63;
  const int wid = tid >> 6;
  const int i0 = blockIdx.x * 128;
  const int n0 = blockIdx.y * 128;
  const int wr = (wid >> 1) * 64;
  const int wc = (wid & 1) * 64;
  f32x4 acc[4][4];
#pragma unroll
  for (int m = 0; m < 4; ++m)
#pragma unroll
    for (int n = 0; n < 4; ++n) acc[m][n] = (f32x4){0.f, 0.f, 0.f, 0.f};
  const int fr = lane & 15;
  const int kg = (lane >> 4) * 8;
  // staging: wave w covers rows w*32..w*32+31 of each tile; lane l hits
  // LDS offset base + l*16B (gload_lds HW layout), matching row=l>>2, col=(l&3)*8.
  const int srow = wid * 32 + (lane >> 2);
  const int skc = (lane & 3) * 8;
  const ushort* Ag = A + (size_t)(i0 + srow) * K + skc;
  const ushort* Bg = B + (size_t)(n0 + srow) * K + skc;
  const int wb = wid * 1024;     // wave-uniform LDS base (shorts)

  // prologue: stage tile 0 into buf 0
  gl_lds16(Ag, &As[0][wb]);
  gl_lds16(Ag + (size_t)16 * K, &As[0][wb + 512]);
  gl_lds16(Bg, &Bs[0][wb]);
  gl_lds16(Bg + (size_t)16 * K, &Bs[0][wb + 512]);
  __syncthreads();               // vmcnt drained -> buf0 ready

  int cur = 0;
  for (int k0 = 0; k0 < K; k0 += 32) {
    if (k0 + 32 < K) {           // stage next tile into the other buffer
      const int nxt = cur ^ 1;
      gl_lds16(Ag + k0 + 32, &As[nxt][wb]);
      gl_lds16(Ag + (size_t)16 * K + k0 + 32, &As[nxt][wb + 512]);
      gl_lds16(Bg + k0 + 32, &Bs[nxt][wb]);
      gl_lds16(Bg + (size_t)16 * K + k0 + 32, &Bs[nxt][wb + 512]);
    }
    bf16x8 af[4], bfr[4];
#pragma unroll
    for (int m = 0; m < 4; ++m)
      af[m] = *(const bf16x8*)&As[cur][(wr + m * 16 + fr) * 32 + kg];
#pragma unroll
    for (int n = 0; n < 4; ++n)
      bfr[n] = *(const bf16x8*)&Bs[cur][(wc + n * 16 + fr) * 32 + kg];
#pragma unroll
    for (int m = 0; m < 4; ++m)
#pragma unroll
      for (int n = 0; n < 4; ++n)
        acc[m][n] = __builtin_amdgcn_mfma_f32_16x16x32_bf16(af[m], bfr[n], acc[m][n], 0, 0, 0);
    __syncthreads();             // drains vmcnt: next buf staged; all reads of cur done
    cur ^= 1;
  }
  const int rq = lane >> 4;
#pragma unroll
  for (int m = 0; m < 4; ++m) {
#pragma unroll
    for (int n = 0; n < 4; ++n) {
#pragma unroll
      for (int rr = 0; rr < 4; ++rr) {
        const int row = i0 + wr + m * 16 + rq * 4 + rr;
        const int col = n0 + wc + n * 16 + fr;
        if (OUT_BF16)
          ((ushort*)Cout)[(size_t)row * N + col] = f2bf(acc[m][n][rr]);
        else
          ((float*)Cout)[(size_t)row * N + col] = acc[m][n][rr];
      }
    }
  }
}

// ---------------- MFMA bf16 flash attention (swapped-operand) ----------------
// Block = 256 threads (4 waves) = one (b,h) x 128 q-rows; wave owns 32 q-rows.
// KV tiles of 64. K staged [kv][d], V staged pre-transposed [d][kv].
// S^T = mfma(K, Q): q = lane-local column -> in-lane softmax reduce.
// Defer-max (THR=8, log2 domain): skip alpha-rescale unless max grows.
// P packed bf16 via cvt_pk -> per-wave LDS slab -> O^T = mfma(V^T, P).
__global__ __launch_bounds__(256, 4) void flash_mfma_k(
    const ushort* __restrict__ Qm, const ushort* __restrict__ Km,
    const ushort* __restrict__ Vt, ushort* __restrict__ Om) {
  __shared__ ushort Ks[64 * 72];
  __shared__ ushort Vs[64 * 72];      // V^T tile: [d][kv]
  __shared__ ushort Ps[4][32 * 72];   // per-wave P tile [q][kv]
  const int tid = threadIdx.x;
  const int lane = tid & 63;
  const int wid = tid >> 6;
  const int bh = blockIdx.x;          // 0..63
  const int qb = blockIdx.y;          // 0..15
  const int bidx = bh >> 4;
  const int h = bh & 15;
  const size_t rowbase = (size_t)bidx * NSEQ;
  const int colbase = h * DHEAD;
  const int fr = lane & 15;           // A-row / B-col select; q = m*16+fr
  const int g = lane >> 4;
  const int kg = g * 8;
  const int q0 = qb * 128 + wid * 32;

  // Q fragments in registers (used as B operand), reused across all KV tiles
  bf16x8 qf[2][2];
#pragma unroll
  for (int m = 0; m < 2; ++m)
#pragma unroll
    for (int ks = 0; ks < 2; ++ks)
      qf[m][ks] = *(const bf16x8*)(Qm + (rowbase + q0 + m * 16 + fr) * (size_t)DIMSZ +
                                   colbase + ks * 32 + kg);

  // O^T accumulator: col = q = m*16+fr, row = d = nd*16 + g*4 + rr
  f32x4 oaccT[2][4];
#pragma unroll
  for (int m = 0; m < 2; ++m)
#pragma unroll
    for (int n = 0; n < 4; ++n) oaccT[m][n] = (f32x4){0.f, 0.f, 0.f, 0.f};
  float m2[2] = {-1e30f, -1e30f};     // running max, log2-scaled domain
  float l_run[2] = {0.f, 0.f};
  const float c1 = 0.125f * 1.44269504088896340736f;  // scale * log2(e)

  const ushort* Kg = Km + rowbase * DIMSZ + colbase;
  const ushort* Vg = Vt + (size_t)bh * DHEAD * NSEQ;
  const int sr = tid >> 3;            // 0..31 staging row
  const int c8 = (tid & 7) * 8;

  // prologue: load tile 0
  uint4 k0 = *(const uint4*)(Kg + (size_t)sr * DIMSZ + c8);
  uint4 k1 = *(const uint4*)(Kg + (size_t)(sr + 32) * DIMSZ + c8);
  uint4 v0 = *(const uint4*)(Vg + (size_t)sr * NSEQ + c8);
  uint4 v1 = *(const uint4*)(Vg + (size_t)(sr + 32) * NSEQ + c8);

  for (int kt = 0; kt < NSEQ / 64; ++kt) {
    __syncthreads();                  // prev tile's LDS reads done
    *(uint4*)&Ks[sr * 72 + c8] = k0;
    *(uint4*)&Ks[(sr + 32) * 72 + c8] = k1;
    *(uint4*)&Vs[sr * 72 + c8] = v0;
    *(uint4*)&Vs[(sr + 32) * 72 + c8] = v1;
    __syncthreads();
    if (kt + 1 < NSEQ / 64) {         // prefetch next tile under compute
      k0 = *(const uint4*)(Kg + (size_t)((kt + 1) * 64 + sr) * DIMSZ + c8);
      k1 = *(const uint4*)(Kg + (size_t)((kt + 1) * 64 + sr + 32) * DIMSZ + c8);
      v0 = *(const uint4*)(Vg + (size_t)sr * NSEQ + (kt + 1) * 64 + c8);
      v1 = *(const uint4*)(Vg + (size_t)(sr + 32) * NSEQ + (kt + 1) * 64 + c8);
    }

    // ---- S^T = K Q^T : s[m][n][rr] = S[q=m*16+fr][kv=n*16+g*4+rr] ----
    f32x4 s[2][4];
#pragma unroll
    for (int m = 0; m < 2; ++m)
#pragma unroll
      for (int n = 0; n < 4; ++n) s[m][n] = (f32x4){0.f, 0.f, 0.f, 0.f};
    __builtin_amdgcn_s_setprio(1);
#pragma unroll
    for (int ks = 0; ks < 2; ++ks) {
      bf16x8 ak[4];
#pragma unroll
      for (int n = 0; n < 4; ++n)
        ak[n] = *(const bf16x8*)&Ks[(n * 16 + fr) * 72 + ks * 32 + kg];
#pragma unroll
      for (int m = 0; m < 2; ++m)
#pragma unroll
        for (int n = 0; n < 4; ++n)
          s[m][n] = __builtin_amdgcn_mfma_f32_16x16x32_bf16(ak[n], qf[m][ks], s[m][n], 0, 0, 0);
    }
    __builtin_amdgcn_s_setprio(0);

    // ---- online softmax, kv lane-local; defer-max (THR=8 in log2 domain) ----
#pragma unroll
    for (int m = 0; m < 2; ++m) {
      float tm = fmaxf(fmaxf(fmaxf(s[m][0][0], s[m][0][1]), fmaxf(s[m][0][2], s[m][0][3])),
                       fmaxf(fmaxf(s[m][1][0], s[m][1][1]), fmaxf(s[m][1][2], s[m][1][3])));
      tm = fmaxf(tm,
                 fmaxf(fmaxf(fmaxf(s[m][2][0], s[m][2][1]), fmaxf(s[m][2][2], s[m][2][3])),
                       fmaxf(fmaxf(s[m][3][0], s[m][3][1]), fmaxf(s[m][3][2], s[m][3][3]))));
      tm = fmaxf(tm, __shfl_xor(tm, 16));
      tm = fmaxf(tm, __shfl_xor(tm, 32));
      const float tm2 = tm * c1;
      if (!__all(tm2 <= m2[m] + 8.0f)) {  // wave-uniform: rescale only on growth
        const float mn2 = fmaxf(m2[m], tm2);
        const float al = exp2f(m2[m] - mn2);
        l_run[m] *= al;
        m2[m] = mn2;
#pragma unroll
        for (int n = 0; n < 4; ++n) oaccT[m][n] *= al;
      }
      const float mref = m2[m];
      float p[4][4];
#pragma unroll
      for (int n = 0; n < 4; ++n)
#pragma unroll
        for (int rr = 0; rr < 4; ++rr) {
          p[n][rr] = exp2f(fmaf(s[m][n][rr], c1, -mref));
          s[m][n][rr] = p[n][rr];
        }
      // tree-shaped sum (short dependency chain)
      const float t0 = (p[0][0] + p[0][1]) + (p[0][2] + p[0][3]);
      const float t1 = (p[1][0] + p[1][1]) + (p[1][2] + p[1][3]);
      const float t2 = (p[2][0] + p[2][1]) + (p[2][2] + p[2][3]);
      const float t3 = (p[3][0] + p[3][1]) + (p[3][2] + p[3][3]);
      float ps = (t0 + t1) + (t2 + t3);
      ps += __shfl_xor(ps, 16);
      ps += __shfl_xor(ps, 32);
      l_run[m] += ps;
    }

    // ---- P^T -> Ps[wid] as [q][kv], packed b64 writes ----
    ushort* pw = &Ps[wid][0];
#pragma unroll
    for (int m = 0; m < 2; ++m)
#pragma unroll
      for (int n = 0; n < 4; ++n) {
        uint2 w;
        w.x = cvt_pk_bf16(s[m][n][0], s[m][n][1]);
        w.y = cvt_pk_bf16(s[m][n][2], s[m][n][3]);
        *(uint2*)&pw[(m * 16 + fr) * 72 + n * 16 + g * 4] = w;
      }

    // ---- O^T += V^T P : oaccT[m][nd], col=q=m*16+fr, row=d=nd*16+g*4+rr ----
    __builtin_amdgcn_s_setprio(1);
#pragma unroll
    for (int ks = 0; ks < 2; ++ks) {
      bf16x8 av[4], pb[2];
#pragma unroll
      for (int nd = 0; nd < 4; ++nd)
        av[nd] = *(const bf16x8*)&Vs[(nd * 16 + fr) * 72 + ks * 32 + kg];
#pragma unroll
      for (int m = 0; m < 2; ++m)
        pb[m] = *(const bf16x8*)&Ps[wid][(m * 16 + fr) * 72 + ks * 32 + kg];
#pragma unroll
      for (int m = 0; m < 2; ++m)
#pragma unroll
        for (int nd = 0; nd < 4; ++nd)
          oaccT[m][nd] = __builtin_amdgcn_mfma_f32_16x16x32_bf16(av[nd], pb[m], oaccT[m][nd], 0, 0, 0);
    }
    __builtin_amdgcn_s_setprio(0);
  }

  // ---- epilogue: O / l, packed b64 global writes ----
#pragma unroll
  for (int m = 0; m < 2; ++m) {
    const float invl = 1.0f / l_run[m];
    const size_t row = rowbase + q0 + m * 16 + fr;
#pragma unroll
    for (int nd = 0; nd < 4; ++nd) {
      uint2 w;
      w.x = cvt_pk_bf16(oaccT[m][nd][0] * invl, oaccT[m][nd][1] * invl);
      w.y = cvt_pk_bf16(oaccT[m][nd][2] * invl, oaccT[m][nd][3] * invl);
      *(uint2*)(Om + row * DIMSZ + colbase + nd * 16 + g * 4) = w;
    }
  }
}

extern "C" void kernel_launch(void* const* d_in, const int* in_sizes, int n_in,
                              void* d_out, int out_size, void* d_ws, size_t ws_size,
                              hipStream_t stream) {
  (void)in_sizes; (void)n_in; (void)out_size; (void)ws_size;
  const float* x     = (const float*)d_in[0];
  const float* ln_g  = (const float*)d_in[1];
  const float* ln_b  = (const float*)d_in[2];
  const float* q_key = (const float*)d_in[3];
  const float* q_val = (const float*)d_in[4];
  const float* k_key = (const float*)d_in[5];
  const float* k_val = (const float*)d_in[6];
  const float* v_key = (const float*)d_in[7];
  const float* v_val = (const float*)d_in[8];
  const float* o_key = (const float*)d_in[9];
  const float* o_val = (const float*)d_in[10];
  float* out = (float*)d_out;

  char* ws = (char*)d_ws;
  const size_t MB = 1024 * 1024;
  ushort* xn    = (ushort*)(ws + 0 * MB);    // 16MB: x_norm bf16 [8192][1024]
  ushort* wkey  = (ushort*)(ws + 16 * MB);   // 8MB: 4x key bf16 [1024][1024]
  ushort* wvalT = (ushort*)(ws + 24 * MB);   // 8MB: 4x val^T bf16 [1024][1024]
  ushort* gelu  = (ushort*)(ws + 32 * MB);   // 16MB: gelu(sim/nrm) bf16
  ushort* qb    = (ushort*)(ws + 48 * MB);   // 16MB
  ushort* kb    = (ushort*)(ws + 64 * MB);   // 16MB
  ushort* vb    = (ushort*)(ws + 80 * MB);   // 16MB
  ushort* aout  = (ushort*)(ws + 96 * MB);   // 16MB: attention output bf16
  // vt aliases gelu: gelu contents are dead between the last pre-attn gemm
  // and the post-attn normgelu, which is exactly vt's live range.
  ushort* vt    = gelu;                      // 16MB: V^T bf16 [64 bh][64 d][2048 n]
  float* sim = (float*)d_out;                // reuse d_out (32MB f32) as sim scratch

  const int NW = DIMSZ * DIMSZ;

  layernorm_k<<<BN_TOT, 256, 0, stream>>>(x, ln_g, ln_b, xn);
  cvt_k<<<1024, 256, 0, stream>>>(q_key, wkey + 0 * (size_t)NW, NW);
  cvt_k<<<1024, 256, 0, stream>>>(k_key, wkey + 1 * (size_t)NW, NW);
  cvt_k<<<1024, 256, 0, stream>>>(v_key, wkey + 2 * (size_t)NW, NW);
  cvt_k<<<1024, 256, 0, stream>>>(o_key, wkey + 3 * (size_t)NW, NW);
  dim3 tg(32, 32);
  transpose_cvt_k<<<tg, 256, 0, stream>>>(q_val, wvalT + 0 * (size_t)NW);
  transpose_cvt_k<<<tg, 256, 0, stream>>>(k_val, wvalT + 1 * (size_t)NW);
  transpose_cvt_k<<<tg, 256, 0, stream>>>(v_val, wvalT + 2 * (size_t)NW);
  transpose_cvt_k<<<tg, 256, 0, stream>>>(o_val, wvalT + 3 * (size_t)NW);

  dim3 gg(BN_TOT / 128, DIMSZ / 128);
  ushort* outs[3] = {qb, kb, vb};
  for (int t = 0; t < 3; ++t) {
    gemm_nt_k<0><<<gg, 256, 0, stream>>>(xn, wkey + t * (size_t)NW, sim, BN_TOT, DIMSZ, DIMSZ);
    normgelu_k<<<BN_TOT, 256, 0, stream>>>(sim, gelu);
    gemm_nt_k<1><<<gg, 256, 0, stream>>>(gelu, wvalT + t * (size_t)NW, outs[t], BN_TOT, DIMSZ, DIMSZ);
  }
  transpose_v_k<<<dim3(64, 64, 2), 256, 0, stream>>>(vb, vt);
  flash_mfma_k<<<dim3(64, 16), 256, 0, stream>>>(qb, kb, vt, aout);
  gemm_nt_k<0><<<gg, 256, 0, stream>>>(aout, wkey + 3 * (size_t)NW, sim, BN_TOT, DIMSZ, DIMSZ);
  normgelu_k<<<BN_TOT, 256, 0, stream>>>(sim, gelu);
  gemm_nt_k<0><<<gg, 256, 0, stream>>>(gelu, wvalT + 3 * (size_t)NW, (void*)out, BN_TOT, DIMSZ, DIMSZ);
}